// Round 7
// baseline (362.033 us; speedup 1.0000x reference)
//
#include <hip/hip_runtime.h>
#include <math.h>

#define UNITS 80
#define LATENT 128
#define IN_DIM 256
#define BATCH 8192
#define SEQ 256
#define G 320           // 4*UNITS
#define H2 160          // 2*UNITS
#define ROW_F4 (SEQ * UNITS / 4)        // 5120 f4 per batch row
#define BODY_F4 ((SEQ - 1) * UNITS / 4) // 5100 f4 in the s>=1 region

#define TPB 320          // 5 waves; 320 % 20 == 0 (yc f4 period)
#define NW 256           // writer blocks: 1 per CU, fill-mimic
#define ROWS_W (BATCH / NW)   // 32 rows (2.56 MB) contiguous per writer
#define NC 512           // compute blocks
#define ROWS_C (BATCH / NC)   // 16 rows per compute block

typedef float f4 __attribute__((ext_vector_type(4)));

__device__ __forceinline__ float sigf(float v) {
    return 1.0f / (1.0f + __expf(-v));
}

// ---------------------------------------------------------------------------
// Kernel 1: yc = decode_step(ones(128)). Input all-ones => z = colsum(K) + b.
// ---------------------------------------------------------------------------
__global__ __launch_bounds__(640)
void yc_kernel(const float* __restrict__ Kf, const float* __restrict__ bf,
               const float* __restrict__ Kb, const float* __restrict__ bb,
               const float* __restrict__ K1, const float* __restrict__ b1,
               float* __restrict__ yc) {
    __shared__ float z[2 * G];
    __shared__ float h[H2];
    const int t = threadIdx.x;   // 0..639

    {
        const float* K   = (t < G) ? Kf : Kb;
        const float* bia = (t < G) ? bf : bb;
        const int c = (t < G) ? t : t - G;
        float acc = bia[c];
#pragma unroll 8
        for (int l = 0; l < LATENT; ++l) acc += K[l * G + c];
        z[t] = acc;
    }
    __syncthreads();
    if (t < UNITS) {
        h[t] = sigf(z[240 + t]) * sigf(z[t]) * fmaxf(z[160 + t], 0.f);
    } else if (t >= G && t < G + UNITS) {
        const int u = t - G;
        h[UNITS + u] = sigf(z[G + 240 + u]) * sigf(z[G + u]) * fmaxf(z[G + 160 + u], 0.f);
    }
    __syncthreads();
    if (t < G) {
        float acc = b1[t];
#pragma unroll 8
        for (int l = 0; l < H2; ++l) acc = fmaf(h[l], K1[l * G + t], acc);
        z[t] = acc;
    }
    __syncthreads();
    if (t < UNITS) yc[t] = sigf(z[240 + t]) * sigf(z[t]) * fmaxf(z[160 + t], 0.f);
}

// ---------------------------------------------------------------------------
// Kernel 2: two block roles in ONE launch (no kernel-boundary serialization).
//   bid < NW   : writer — sweep a contiguous 32-row slab of the s>=1 region
//                with plain f4 stores (fill-mimic: ~1 block/CU, sequential).
//   bid >= NW  : compute — y0 for 16 rows, compute-first, then s=0 stores.
// ---------------------------------------------------------------------------
__global__ __launch_bounds__(TPB)
void main_kernel(const float* __restrict__ x,
                 const float* __restrict__ Wl, const float* __restrict__ bl,
                 const float* __restrict__ Kf, const float* __restrict__ bf,
                 const float* __restrict__ Kb, const float* __restrict__ bb,
                 const float* __restrict__ K1, const float* __restrict__ b1,
                 const float* __restrict__ yc,
                 float* __restrict__ out) {
    __shared__ float xs[ROWS_C * IN_DIM];     // 16 KB
    __shared__ float lat_s[ROWS_C * LATENT];  // 8 KB
    __shared__ float h_s[ROWS_C * H2];        // 10 KB

    const int t = threadIdx.x;
    const int bid = blockIdx.x;

    if (bid < NW) {
        // ---------------- writer role ----------------
        __shared__ f4 ycs[UNITS / 4];
        if (t < UNITS / 4) ycs[t] = ((const f4*)yc)[t];
        __syncthreads();
        const f4 yv = ycs[t % (UNITS / 4)];   // constant per thread (320%20==0)

        f4* rowp = (f4*)out + (size_t)bid * ROWS_W * ROW_F4 + (UNITS / 4);
        for (int r = 0; r < ROWS_W; ++r) {
#pragma unroll
            for (int k = 0; k < 15; ++k)      // 15*320 = 4800
                rowp[t + k * TPB] = yv;
            if (t < BODY_F4 - 15 * TPB)       // tail: 300
                rowp[t + 15 * TPB] = yv;
            rowp += ROW_F4;
        }
        return;
    }

    // ---------------- compute role: rows R0 .. R0+15 ----------------
    const int R0 = (bid - NW) * ROWS_C;

    // stage x tile (16 rows x 256 f32 = 1024 f4)
    {
        const f4* xg = (const f4*)(x + (size_t)R0 * IN_DIM);
        f4* xs4 = (f4*)xs;
        for (int i = t; i < ROWS_C * IN_DIM / 4; i += TPB) xs4[i] = xg[i];
    }
    __syncthreads();

    // lat = x @ W_lat + b_lat : 16*128 = 2048 outputs
    for (int i = t; i < ROWS_C * LATENT; i += TPB) {
        const int row = i >> 7, col = i & 127;
        float acc = bl[col];
        const float* xr = xs + row * IN_DIM;
#pragma unroll 8
        for (int l = 0; l < IN_DIM; ++l) acc = fmaf(xr[l], Wl[l * LATENT + col], acc);
        lat_s[i] = acc;
    }
    __syncthreads();

    // fw/bw gates: 2*16*80 = 2560 outputs (f gate dead: c0=0; relu(c)=c, c>=0)
    for (int i = t; i < 2 * ROWS_C * UNITS; i += TPB) {
        const int half = (i >= ROWS_C * UNITS);
        const int j = half ? i - ROWS_C * UNITS : i;
        const int row = j / UNITS;
        const int u = j - row * UNITS;
        const float* K   = half ? Kb : Kf;
        const float* bia = half ? bb : bf;
        float ai = 0.f, ac = 0.f, ao = 0.f;
        const float* lr = lat_s + row * LATENT;
#pragma unroll 4
        for (int k = 0; k < LATENT; ++k) {
            const float lv = lr[k];
            ai = fmaf(lv, K[k * G + u], ai);
            ac = fmaf(lv, K[k * G + 160 + u], ac);
            ao = fmaf(lv, K[k * G + 240 + u], ao);
        }
        h_s[row * H2 + half * UNITS + u] =
            sigf(ao + bia[240 + u]) * sigf(ai + bia[u]) * fmaxf(ac + bia[160 + u], 0.f);
    }
    __syncthreads();

    // output LSTM: 16*80 = 1280 outputs into registers, then store s=0 slices
    float yv0 = 0.f, yv1 = 0.f, yv2 = 0.f, yv3 = 0.f;
#pragma unroll
    for (int p = 0; p < 4; ++p) {
        const int i = t + p * TPB;
        const int row = i / UNITS;
        const int u = i - row * UNITS;
        float ai = 0.f, ac = 0.f, ao = 0.f;
        const float* hr = h_s + row * H2;
#pragma unroll 4
        for (int k = 0; k < H2; ++k) {
            const float hv = hr[k];
            ai = fmaf(hv, K1[k * G + u], ai);
            ac = fmaf(hv, K1[k * G + 160 + u], ac);
            ao = fmaf(hv, K1[k * G + 240 + u], ao);
        }
        const float y = sigf(ao + b1[240 + u]) * sigf(ai + b1[u]) * fmaxf(ac + b1[160 + u], 0.f);
        if (p == 0) yv0 = y; else if (p == 1) yv1 = y; else if (p == 2) yv2 = y; else yv3 = y;
    }

    __builtin_amdgcn_sched_barrier(0);   // stores strictly after all load-uses

#pragma unroll
    for (int p = 0; p < 4; ++p) {
        const int i = t + p * TPB;
        const int row = i / UNITS;
        const int u = i - row * UNITS;
        const float y = (p == 0) ? yv0 : (p == 1) ? yv1 : (p == 2) ? yv2 : yv3;
        out[(size_t)(R0 + row) * SEQ * UNITS + u] = y;
    }
}

extern "C" void kernel_launch(void* const* d_in, const int* in_sizes, int n_in,
                              void* d_out, int out_size, void* d_ws, size_t ws_size,
                              hipStream_t stream) {
    const float* x   = (const float*)d_in[0];
    // d_in[1] = size (scalar, fixed 256)
    const float* Wl  = (const float*)d_in[2];
    const float* bl  = (const float*)d_in[3];
    const float* Kf  = (const float*)d_in[4];
    const float* bf  = (const float*)d_in[5];
    const float* Kb  = (const float*)d_in[6];
    const float* bb  = (const float*)d_in[7];
    const float* K1  = (const float*)d_in[8];
    const float* b1  = (const float*)d_in[9];
    float* out = (float*)d_out;
    float* yc  = (float*)d_ws;   // 80 floats

    yc_kernel<<<1, 640, 0, stream>>>(Kf, bf, Kb, bb, K1, b1, yc);
    main_kernel<<<NW + NC, TPB, 0, stream>>>(x, Wl, bl, Kf, bf, Kb, bb, K1, b1, yc, out);
}

// Round 9
// 217.034 us; speedup vs baseline: 1.6681x; 1.6681x over previous
//
#include <hip/hip_runtime.h>
#include <math.h>

#define UNITS 80
#define LATENT 128
#define IN_DIM 256
#define BATCH 8192
#define SEQ 256
#define G 320            // 4*UNITS
#define H2 160           // 2*UNITS
#define ROW_F (SEQ * UNITS)      // 20480 floats per batch row
#define ROW_F4 (ROW_F / 4)       // 5120 f4 per row
#define BODY_F4 ((SEQ - 1) * UNITS / 4)  // 5100 f4 in s>=1 region
#define SPLIT_F4 3840            // store-wave part (60 iters of 64); tail = 1260

#define TPB 512          // 8 waves: 0-3 compute (1 row each), 4-7 store
#define RPB 4            // batch rows per block
#define NBLK (BATCH / RPB)   // 2048

typedef float f4 __attribute__((ext_vector_type(4)));

__device__ __forceinline__ float sigf(float v) {
    return 1.0f / (1.0f + __expf(-v));
}

// intra-wave sync: IR-level memory barrier + MI-level scheduling barrier.
// Cross-lane LDS deps are handled by the DS pipe's per-wave in-order execution.
__device__ __forceinline__ void wave_sync() {
    asm volatile("" ::: "memory");
    __builtin_amdgcn_wave_barrier();
}

// ---------------------------------------------------------------------------
// Kernel 1: yc = decode_step(ones(128)). Input all-ones => z = colsum(K) + b.
// ---------------------------------------------------------------------------
__global__ __launch_bounds__(640)
void yc_kernel(const float* __restrict__ Kf, const float* __restrict__ bf,
               const float* __restrict__ Kb, const float* __restrict__ bb,
               const float* __restrict__ K1, const float* __restrict__ b1,
               float* __restrict__ yc) {
    __shared__ float z[2 * G];
    __shared__ float h[H2];
    const int t = threadIdx.x;   // 0..639

    {
        const float* K   = (t < G) ? Kf : Kb;
        const float* bia = (t < G) ? bf : bb;
        const int c = (t < G) ? t : t - G;
        float acc = bia[c];
#pragma unroll 8
        for (int l = 0; l < LATENT; ++l) acc += K[l * G + c];
        z[t] = acc;
    }
    __syncthreads();
    if (t < UNITS) {
        h[t] = sigf(z[240 + t]) * sigf(z[t]) * fmaxf(z[160 + t], 0.f);
    } else if (t >= G && t < G + UNITS) {
        const int u = t - G;
        h[UNITS + u] = sigf(z[G + 240 + u]) * sigf(z[G + u]) * fmaxf(z[G + 160 + u], 0.f);
    }
    __syncthreads();
    if (t < G) {
        float acc = b1[t];
#pragma unroll 8
        for (int l = 0; l < H2; ++l) acc = fmaf(h[l], K1[l * G + t], acc);
        z[t] = acc;
    }
    __syncthreads();
    if (t < UNITS) yc[t] = sigf(z[240 + t]) * sigf(z[t]) * fmaxf(z[160 + t], 0.f);
}

// ---------------------------------------------------------------------------
// Kernel 2: wave-split roles, zero block barriers.
//   waves 4-7: nt-store body [0,3840) f4 of row R0+(w-4), from t~0.
//   waves 0-3: compute y0 of row R0+w in a private LDS slice, then store the
//              s=0 slice + body tail [3840,5100).
// yc broadcast phase: (64*iter) % 20 cycles {0,4,8,12,16}; preload 5 rotations.
// ---------------------------------------------------------------------------
__global__ __launch_bounds__(TPB, 4)
void main_kernel(const float* __restrict__ x,
                 const float* __restrict__ Wl, const float* __restrict__ bl,
                 const float* __restrict__ Kf, const float* __restrict__ bf,
                 const float* __restrict__ Kb, const float* __restrict__ bb,
                 const float* __restrict__ K1, const float* __restrict__ b1,
                 const float* __restrict__ yc,
                 float* __restrict__ out) {
    // per-compute-wave slice: xs[0..255] | lat[256..383] | h[384..543]
    __shared__ float cws[4][544];    // 8.7 KB

    const int t = threadIdx.x;
    const int lane = t & 63;
    const int w = t >> 6;
    const int R0 = blockIdx.x * RPB;

    // 5 phase-rotated yc f4 values: yvs[p] = yc4[(lane + 4p) % 20]
    f4 yvs[5];
#pragma unroll
    for (int p = 0; p < 5; ++p)
        yvs[p] = ((const f4*)yc)[(lane + 4 * p) % (UNITS / 4)];

    if (w >= 4) {
        // ------------- store wave: body f4 [0, 3840) of one row -------------
        const int row = R0 + (w - 4);
        f4* rowp = (f4*)out + (size_t)row * ROW_F4 + (UNITS / 4);
        for (int g = 0; g < 12; ++g) {
#pragma unroll
            for (int p = 0; p < 5; ++p)
                __builtin_nontemporal_store(yvs[p], rowp + (g * 5 + p) * 64 + lane);
        }
        return;
    }

    // ---------------- compute wave: row R0 + w ----------------
    const int row = R0 + w;
    float* S = cws[w];
    float* lat = S + 256;
    float* h = S + 384;

    // stage x row (64 lanes x f4 = 256 floats)
    ((f4*)S)[lane] = ((const f4*)(x + (size_t)row * IN_DIM))[lane];
    wave_sync();

    // lat = x @ W_lat + b_lat : lane covers cols {lane, lane+64}
    {
        float a0 = bl[lane], a1 = bl[lane + 64];
        for (int l = 0; l < IN_DIM; ++l) {
            const float xv = S[l];
            a0 = fmaf(xv, Wl[l * LATENT + lane], a0);
            a1 = fmaf(xv, Wl[l * LATENT + lane + 64], a1);
        }
        lat[lane] = a0;
        lat[lane + 64] = a1;
    }
    wave_sync();

    // fw/bw gates: h[o], o in {lane, lane+64, lane+128<160}; h = [fw 80 | bw 80]
#pragma unroll
    for (int gidx = 0; gidx < 3; ++gidx) {
        const int o = lane + gidx * 64;
        if (o < H2) {
            const int isbw = (o >= UNITS);
            const int u = isbw ? o - UNITS : o;
            const float* K   = isbw ? Kb : Kf;
            const float* bia = isbw ? bb : bf;
            float ai = bia[u], ac = bia[160 + u], ao = bia[240 + u];
            for (int k = 0; k < LATENT; ++k) {
                const float lv = lat[k];
                ai = fmaf(lv, K[k * G + u], ai);
                ac = fmaf(lv, K[k * G + 160 + u], ac);
                ao = fmaf(lv, K[k * G + 240 + u], ao);
            }
            h[o] = sigf(ao) * sigf(ai) * fmaxf(ac, 0.f);   // f dead (c0=0), relu(c)=c
        }
    }
    wave_sync();

    // output LSTM: units u0 = lane (<64), u1 = 64+lane (lane<16; clamped else)
    {
        const int u0 = lane;
        const int u1 = (lane < 16) ? 64 + lane : 79;   // clamp: discarded for lane>=16
        float ai0 = b1[u0], ac0 = b1[160 + u0], ao0 = b1[240 + u0];
        float ai1 = b1[u1], ac1 = b1[160 + u1], ao1 = b1[240 + u1];
        for (int k = 0; k < H2; ++k) {
            const float hv = h[k];
            ai0 = fmaf(hv, K1[k * G + u0], ai0);
            ac0 = fmaf(hv, K1[k * G + 160 + u0], ac0);
            ao0 = fmaf(hv, K1[k * G + 240 + u0], ao0);
            ai1 = fmaf(hv, K1[k * G + u1], ai1);
            ac1 = fmaf(hv, K1[k * G + 160 + u1], ac1);
            ao1 = fmaf(hv, K1[k * G + 240 + u1], ao1);
        }
        const float y0v = sigf(ao0) * sigf(ai0) * fmaxf(ac0, 0.f);
        const float y1v = sigf(ao1) * sigf(ai1) * fmaxf(ac1, 0.f);
        // park y in the (dead) xs region, then vector-store the s=0 slice
        S[u0] = y0v;
        if (lane < 16) S[u1] = y1v;
    }
    wave_sync();

    if (lane < UNITS / 4) {
        const f4 yq = ((const f4*)S)[lane];
        __builtin_nontemporal_store(yq, (f4*)(out + (size_t)row * ROW_F) + lane);
    }

    // body tail f4 [3840, 5100): phase (3840 + 64i) % 20 = (4i + lane) % 20
    {
        f4* rowp = (f4*)out + (size_t)row * ROW_F4 + (UNITS / 4);
        for (int g = 0; g < 4; ++g) {
#pragma unroll
            for (int p = 0; p < 5; ++p) {
                const int j = SPLIT_F4 + (g * 5 + p) * 64 + lane;
                if (j < BODY_F4) __builtin_nontemporal_store(yvs[p], rowp + j);
            }
        }
    }
}

extern "C" void kernel_launch(void* const* d_in, const int* in_sizes, int n_in,
                              void* d_out, int out_size, void* d_ws, size_t ws_size,
                              hipStream_t stream) {
    const float* x   = (const float*)d_in[0];
    // d_in[1] = size (scalar, fixed 256)
    const float* Wl  = (const float*)d_in[2];
    const float* bl  = (const float*)d_in[3];
    const float* Kf  = (const float*)d_in[4];
    const float* bf  = (const float*)d_in[5];
    const float* Kb  = (const float*)d_in[6];
    const float* bb  = (const float*)d_in[7];
    const float* K1  = (const float*)d_in[8];
    const float* b1  = (const float*)d_in[9];
    float* out = (float*)d_out;
    float* yc  = (float*)d_ws;   // 80 floats

    yc_kernel<<<1, 640, 0, stream>>>(Kf, bf, Kb, bb, K1, b1, yc);
    main_kernel<<<NBLK, TPB, 0, stream>>>(x, Wl, bl, Kf, bf, Kb, bb, K1, b1, yc, out);
}